// Round 10
// baseline (69.972 us; speedup 1.0000x reference)
//
#include <hip/hip_runtime.h>
#include <hip/hip_bf16.h>
#include <stdint.h>

// Problem constants
#define B_DIM 8
#define T_DIM 2048
#define INNER 256      // IN_DIM == HEAD_TOTAL == 256
#define NEGV (-1e9f)
#define SCALE 0.0625f  // 1/sqrt(256)

typedef __bf16 bf16_t;
typedef __bf16 bf16x8 __attribute__((ext_vector_type(8)));
typedef float f32x4 __attribute__((ext_vector_type(4)));

// Stage a 128x64 tile from FP32 global into bf16 LDS (reg-staged convert),
// 256 threads. Issue all 8 global loads first, then cvt + ds_write.
__device__ inline void stage_tile_cvt(const float* gbase, int ldg,
                                      bf16_t (*lds)[64], int tid) {
  const int l = tid & 63;
  const int w = tid >> 6;
  const int sub = l >> 3;
  const int ce = (l & 7) * 8;
  f32x4 v[4][2];
#pragma unroll
  for (int i = 0; i < 4; ++i) {
    const int row = (i * 4 + w) * 8 + sub;
    const float* p = gbase + (size_t)row * ldg + ce;
    v[i][0] = *(const f32x4*)p;
    v[i][1] = *(const f32x4*)(p + 4);
  }
#pragma unroll
  for (int i = 0; i < 4; ++i) {
    const int row = (i * 4 + w) * 8 + sub;
    bf16x8 o;
#pragma unroll
    for (int j = 0; j < 4; ++j) {
      o[j]     = (bf16_t)v[i][0][j];
      o[4 + j] = (bf16_t)v[i][1][j];
    }
    *(bf16x8*)&lds[row][ce] = o;
  }
}

// ---- Kernel 1: Q = x @ Wq^T, K = x @ Wk^T, reading FP32 inputs directly ----
// fp32->bf16 conversion fused into staging (round-7 verified, 47.1us config).
// x streams from HBM (not cache-resident) so LDS staging pays here.
__global__ __launch_bounds__(256) void proj_kernel(
    const float* __restrict__ x, const float* __restrict__ Wq,
    const float* __restrict__ Wk, bf16_t* __restrict__ Q,
    bf16_t* __restrict__ Kout) {
  __shared__ bf16_t Al[128][64];
  __shared__ bf16_t Bl[128][64];
  const int tid = threadIdx.x;
  const int mrow = blockIdx.x * 128;   // row in [0, B*T)
  const int ncol = blockIdx.y * 128;   // out-feature
  const float* W = blockIdx.z ? Wk : Wq;
  bf16_t* O = blockIdx.z ? Kout : Q;

  const int l = tid & 63, wid = tid >> 6, wr = wid >> 1, wc = wid & 1;
  const int lr = l & 15, kg = l >> 4;

  f32x4 acc[4][4] = {};
  const float* Ax = x + (size_t)mrow * INNER;
  const float* Bw = W + (size_t)ncol * INNER;
#pragma unroll
  for (int k0 = 0; k0 < INNER; k0 += 64) {
    stage_tile_cvt(Ax + k0, INNER, Al, tid);
    stage_tile_cvt(Bw + k0, INNER, Bl, tid);
    __syncthreads();
#pragma unroll
    for (int kk = 0; kk < 2; ++kk) {
      bf16x8 af[4], bfm[4];
#pragma unroll
      for (int f = 0; f < 4; ++f) {
        af[f]  = *(const bf16x8*)&Al[wr * 64 + f * 16 + lr][kk * 32 + kg * 8];
        bfm[f] = *(const bf16x8*)&Bl[wc * 64 + f * 16 + lr][kk * 32 + kg * 8];
      }
#pragma unroll
      for (int m = 0; m < 4; ++m)
#pragma unroll
        for (int n = 0; n < 4; ++n)
          acc[m][n] = __builtin_amdgcn_mfma_f32_16x16x32_bf16(
              af[m], bfm[n], acc[m][n], 0, 0, 0);
    }
    __syncthreads();
  }

#pragma unroll
  for (int m = 0; m < 4; ++m)
#pragma unroll
    for (int n = 0; n < 4; ++n)
#pragma unroll
      for (int j = 0; j < 4; ++j) {
        // C/D layout: col = lane&15, row = (lane>>4)*4 + reg  [m89]
        int r = mrow + wr * 64 + m * 16 + kg * 4 + j;
        int c = ncol + wc * 64 + n * 16 + lr;
        O[(size_t)r * INNER + c] = (bf16_t)acc[m][n][j];
      }
}

// ---- Kernel 2: E = Q @ K^T * scale (+ diag mask); lower tiles fill -1e9 ----
// ZERO LDS, ZERO barriers: with the batch-per-XCD pin (`b = bid & 7`),
// Q_b + K_b = 2 MB is resident in that XCD's 4 MiB L2, so each lane loads
// its MFMA fragments straight from global (16B bf16x8 loads; L2 serves the
// 64B/row segments at ~35 TB/s). LDS staging of cache-resident data is pure
// overhead [guide common-mistake #7, m169]: it added 8 barrier+vmcnt(0)
// drains per block and bunched the epilogue stores. Waves now run free.
__global__ __launch_bounds__(256) void scores_kernel(
    const bf16_t* __restrict__ Q, const bf16_t* __restrict__ Kin,
    float* __restrict__ E) {
  const int bid = blockIdx.x;
  const int b = bid & 7;       // batch == XCD
  const int lid = bid >> 3;    // 0..255 tile id within batch
  const int rt = lid >> 4;     // row tile (t)
  const int ct = lid & 15;     // col tile (s)
  const int tid = threadIdx.x;
  float* Eb = E + (size_t)b * T_DIM * T_DIM;
  const int trow = rt * 128, scol = ct * 128;

  if (ct < rt) {
    // strictly below diagonal: exact -1e9 fill (512B row segments);
    // overlaps compute blocks' read/MFMA phases in the same dispatch.
    const f32x4 neg = {NEGV, NEGV, NEGV, NEGV};
#pragma unroll
    for (int it = 0; it < 16; ++it) {
      int idx = it * 256 + tid;          // 0..4095 float4 slots
      int r = idx >> 5, c4 = idx & 31;
      *(f32x4*)&Eb[(size_t)(trow + r) * T_DIM + scol + c4 * 4] = neg;
    }
    return;
  }

  const int l = tid & 63, wid = tid >> 6, wr = wid >> 1, wc = wid & 1;
  const int lr = l & 15, kg = l >> 4;

  // Per-thread fragment row pointers (16B-aligned).
  const bf16_t* qrow[4];
  const bf16_t* krow[4];
#pragma unroll
  for (int f = 0; f < 4; ++f) {
    qrow[f] = Q + ((size_t)b * T_DIM + trow + wr * 64 + f * 16 + lr) * INNER
              + kg * 8;
    krow[f] = Kin + ((size_t)b * T_DIM + scol + wc * 64 + f * 16 + lr) * INNER
              + kg * 8;
  }

  f32x4 acc[4][4] = {};
#pragma unroll
  for (int kc = 0; kc < 8; ++kc) {     // k = kc*32
    bf16x8 af[4], bfm[4];
#pragma unroll
    for (int f = 0; f < 4; ++f) af[f]  = *(const bf16x8*)(qrow[f] + kc * 32);
#pragma unroll
    for (int f = 0; f < 4; ++f) bfm[f] = *(const bf16x8*)(krow[f] + kc * 32);
#pragma unroll
    for (int m = 0; m < 4; ++m)
#pragma unroll
      for (int n = 0; n < 4; ++n)
        acc[m][n] = __builtin_amdgcn_mfma_f32_16x16x32_bf16(
            af[m], bfm[n], acc[m][n], 0, 0, 0);
  }

  const bool diag = (ct == rt);
#pragma unroll
  for (int m = 0; m < 4; ++m)
#pragma unroll
    for (int n = 0; n < 4; ++n)
#pragma unroll
      for (int j = 0; j < 4; ++j) {
        int t = trow + wr * 64 + m * 16 + kg * 4 + j;
        int s = scol + wc * 64 + n * 16 + lr;
        float v = acc[m][n][j] * SCALE;
        if (diag && s < t) v += NEGV;
        Eb[(size_t)t * T_DIM + s] = v;
      }
}

extern "C" void kernel_launch(void* const* d_in, const int* in_sizes, int n_in,
                              void* d_out, int out_size, void* d_ws,
                              size_t ws_size, hipStream_t stream) {
  const float* x  = (const float*)d_in[0];   // [8,2048,256] fp32
  const float* Wq = (const float*)d_in[1];   // [256,256] fp32
  const float* Wk = (const float*)d_in[2];   // [256,256] fp32
  float* out = (float*)d_out;

  const size_t n_x = (size_t)B_DIM * T_DIM * INNER;  // 4,194,304

  // Workspace layout (bf16): Q | K  (16.8 MB)
  bf16_t* Q = (bf16_t*)d_ws;
  bf16_t* K = Q + n_x;

  dim3 g1(B_DIM * T_DIM / 128, INNER / 128, 2);  // (128, 2, 2) = 512 blocks
  proj_kernel<<<g1, dim3(256), 0, stream>>>(x, Wq, Wk, Q, K);

  scores_kernel<<<2048, 256, 0, stream>>>(Q, K, out);
}

// Round 11
// 47.549 us; speedup vs baseline: 1.4716x; 1.4716x over previous
//
#include <hip/hip_runtime.h>
#include <hip/hip_bf16.h>
#include <stdint.h>

// Problem constants
#define B_DIM 8
#define T_DIM 2048
#define INNER 256      // IN_DIM == HEAD_TOTAL == 256
#define NEGV (-1e9f)
#define SCALE 0.0625f  // 1/sqrt(256)

typedef __bf16 bf16_t;
typedef __bf16 bf16x8 __attribute__((ext_vector_type(8)));
typedef float f32x4 __attribute__((ext_vector_type(4)));

// ---- async global->LDS, 16B per lane (global_load_lds_dwordx4) ----
__device__ inline void gload_lds16(const bf16_t* g, bf16_t* lds) {
  __builtin_amdgcn_global_load_lds(
      (__attribute__((address_space(1))) void*)(g),
      (__attribute__((address_space(3))) void*)(lds),
      16, 0, 0);
}

// Stage a 128x64 bf16 tile (row stride ldg elements) into lds[128][64].
// Linear LDS layout; wave-uniform LDS base + lane*16 (HW requirement).
__device__ inline void stage_tile(const bf16_t* gbase, int ldg,
                                  bf16_t (*lds)[64], int tid) {
  const int l = tid & 63;
  const int w = tid >> 6;
  const int sub = l >> 3;        // row within 8-row chunk
  const int ce = (l & 7) * 8;    // starting column element (8 bf16 = 16B)
#pragma unroll
  for (int i = 0; i < 4; ++i) {
    const int chunk = i * 4 + w;               // 0..15, uniform per wave
    const int row = chunk * 8 + sub;
    gload_lds16(gbase + (size_t)row * ldg + ce, &lds[chunk * 8][0]);
  }
}

// Stage a 128x64 tile from FP32 global into bf16 LDS (reg-staged convert),
// 256 threads. Issue all 8 global loads first, then cvt + ds_write.
__device__ inline void stage_tile_cvt(const float* gbase, int ldg,
                                      bf16_t (*lds)[64], int tid) {
  const int l = tid & 63;
  const int w = tid >> 6;
  const int sub = l >> 3;
  const int ce = (l & 7) * 8;
  f32x4 v[4][2];
#pragma unroll
  for (int i = 0; i < 4; ++i) {
    const int row = (i * 4 + w) * 8 + sub;
    const float* p = gbase + (size_t)row * ldg + ce;
    v[i][0] = *(const f32x4*)p;
    v[i][1] = *(const f32x4*)(p + 4);
  }
#pragma unroll
  for (int i = 0; i < 4; ++i) {
    const int row = (i * 4 + w) * 8 + sub;
    bf16x8 o;
#pragma unroll
    for (int j = 0; j < 4; ++j) {
      o[j]     = (bf16_t)v[i][0][j];
      o[4 + j] = (bf16_t)v[i][1][j];
    }
    *(bf16x8*)&lds[row][ce] = o;
  }
}

// 128x128 output tile GEMM, C = A * B^T, both A and Bm are [row][k] bf16.
// Single-buffered m97 structure (32KB LDS -> 5 blocks/CU). Rounds 3/8/10
// showed dbuf, wider tiles, and no-LDS all regress this shape: LDS staging
// is the coalescer and TLP hides its latency.
template <int KDIM>
__device__ inline void gemm_bt_128(const bf16_t* A, const bf16_t* Bm, int ld,
                                   bf16_t (*Al)[64], bf16_t (*Bl)[64],
                                   f32x4 acc[4][4], int tid) {
  const int l = tid & 63;
  const int wid = tid >> 6;
  const int wr = wid >> 1, wc = wid & 1;
  const int lr = l & 15;   // fragment row (A) / col (B) lane
  const int kg = l >> 4;   // k-chunk group 0..3
#pragma unroll
  for (int k0 = 0; k0 < KDIM; k0 += 64) {
    stage_tile(A + k0, ld, Al, tid);
    stage_tile(Bm + k0, ld, Bl, tid);
    __syncthreads();   // compiler drains vmcnt(0) before s_barrier
#pragma unroll
    for (int kk = 0; kk < 2; ++kk) {
      bf16x8 af[4], bfm[4];
#pragma unroll
      for (int f = 0; f < 4; ++f) {
        af[f]  = *(const bf16x8*)&Al[wr * 64 + f * 16 + lr][kk * 32 + kg * 8];
        bfm[f] = *(const bf16x8*)&Bl[wc * 64 + f * 16 + lr][kk * 32 + kg * 8];
      }
#pragma unroll
      for (int m = 0; m < 4; ++m)
#pragma unroll
        for (int n = 0; n < 4; ++n)
          acc[m][n] = __builtin_amdgcn_mfma_f32_16x16x32_bf16(
              af[m], bfm[n], acc[m][n], 0, 0, 0);
    }
    __syncthreads();
  }
}

// ---- Kernel 1: Q = x @ Wq^T, K = x @ Wk^T, reading FP32 inputs directly ----
// fp32->bf16 conversion fused into staging (round-7 verified). 1-D grid,
// XCD-ALIGNED: `b = bid & 7` makes XCD b produce batch b's Q/K panels, so
// the writes land in XCD b's L2 (2 MB fits 4 MiB) — the same L2 that the
// batch-pinned scores kernel reads from. Producer/consumer L2 affinity.
__global__ __launch_bounds__(256) void proj_kernel(
    const float* __restrict__ x, const float* __restrict__ Wq,
    const float* __restrict__ Wk, bf16_t* __restrict__ Q,
    bf16_t* __restrict__ Kout) {
  const int bid = blockIdx.x;       // 0..511
  const int b = bid & 7;            // batch == XCD
  const int rem = bid >> 3;         // 0..63
  const int pl = rem & 15;          // row-panel within batch
  const int ncol = ((rem >> 4) & 1) * 128;
  const int z = rem >> 5;           // 0 -> Q, 1 -> K
  const int mrow = (b * 16 + pl) * 128;   // row in [0, B*T)

  __shared__ bf16_t Al[128][64];
  __shared__ bf16_t Bl[128][64];
  const int tid = threadIdx.x;
  const float* W = z ? Wk : Wq;
  bf16_t* O = z ? Kout : Q;

  const int l = tid & 63, wid = tid >> 6, wr = wid >> 1, wc = wid & 1;
  const int lr = l & 15, kg = l >> 4;

  f32x4 acc[4][4] = {};
  const float* Ax = x + (size_t)mrow * INNER;
  const float* Bw = W + (size_t)ncol * INNER;
#pragma unroll
  for (int k0 = 0; k0 < INNER; k0 += 64) {
    stage_tile_cvt(Ax + k0, INNER, Al, tid);
    stage_tile_cvt(Bw + k0, INNER, Bl, tid);
    __syncthreads();
#pragma unroll
    for (int kk = 0; kk < 2; ++kk) {
      bf16x8 af[4], bfm[4];
#pragma unroll
      for (int f = 0; f < 4; ++f) {
        af[f]  = *(const bf16x8*)&Al[wr * 64 + f * 16 + lr][kk * 32 + kg * 8];
        bfm[f] = *(const bf16x8*)&Bl[wc * 64 + f * 16 + lr][kk * 32 + kg * 8];
      }
#pragma unroll
      for (int m = 0; m < 4; ++m)
#pragma unroll
        for (int n = 0; n < 4; ++n)
          acc[m][n] = __builtin_amdgcn_mfma_f32_16x16x32_bf16(
              af[m], bfm[n], acc[m][n], 0, 0, 0);
    }
    __syncthreads();
  }

#pragma unroll
  for (int m = 0; m < 4; ++m)
#pragma unroll
    for (int n = 0; n < 4; ++n)
#pragma unroll
      for (int j = 0; j < 4; ++j) {
        // C/D layout: col = lane&15, row = (lane>>4)*4 + reg  [m89]
        int r = mrow + wr * 64 + m * 16 + kg * 4 + j;
        int c = ncol + wc * 64 + n * 16 + lr;
        O[(size_t)r * INNER + c] = (bf16_t)acc[m][n][j];
      }
}

// ---- Kernel 2: E = Q @ K^T * scale (+ diag mask); lower tiles fill -1e9 ----
// Round-7 verified form. 1-D grid, 2048 blocks. XCD pin `b = bid & 7`
// (Q_b + K_b = 2 MB in the XCD's 4 MiB L2 — now written there by proj too).
// Lower-triangle blocks do the -1e9 fill so fill writes overlap compute
// blocks' stage/MFMA phases.
__global__ __launch_bounds__(256) void scores_kernel(
    const bf16_t* __restrict__ Q, const bf16_t* __restrict__ Kin,
    float* __restrict__ E) {
  const int bid = blockIdx.x;
  const int b = bid & 7;       // batch == XCD
  const int lid = bid >> 3;    // 0..255 tile id within batch
  const int rt = lid >> 4;     // row tile (t)
  const int ct = lid & 15;     // col tile (s)
  const int tid = threadIdx.x;
  float* Eb = E + (size_t)b * T_DIM * T_DIM;
  const int trow = rt * 128, scol = ct * 128;

  if (ct < rt) {
    // strictly below diagonal: exact -1e9 fill (512B row segments)
    const f32x4 neg = {NEGV, NEGV, NEGV, NEGV};
#pragma unroll
    for (int it = 0; it < 16; ++it) {
      int idx = it * 256 + tid;          // 0..4095 float4 slots
      int r = idx >> 5, c4 = idx & 31;
      *(f32x4*)&Eb[(size_t)(trow + r) * T_DIM + scol + c4 * 4] = neg;
    }
    return;
  }

  __shared__ bf16_t Al[128][64];
  __shared__ bf16_t Bl[128][64];
  f32x4 acc[4][4] = {};
  const bf16_t* Qb = Q + (size_t)b * T_DIM * INNER;
  const bf16_t* Kb = Kin + (size_t)b * T_DIM * INNER;
  gemm_bt_128<INNER>(Qb + (size_t)trow * INNER, Kb + (size_t)scol * INNER,
                     INNER, Al, Bl, acc, tid);

  const int l = tid & 63, wid = tid >> 6, wr = wid >> 1, wc = wid & 1;
  const int lr = l & 15, kg = l >> 4;
  const bool diag = (ct == rt);
#pragma unroll
  for (int m = 0; m < 4; ++m)
#pragma unroll
    for (int n = 0; n < 4; ++n)
#pragma unroll
      for (int j = 0; j < 4; ++j) {
        int t = trow + wr * 64 + m * 16 + kg * 4 + j;
        int s = scol + wc * 64 + n * 16 + lr;
        float v = acc[m][n][j] * SCALE;
        if (diag && s < t) v += NEGV;
        Eb[(size_t)t * T_DIM + s] = v;
      }
}

extern "C" void kernel_launch(void* const* d_in, const int* in_sizes, int n_in,
                              void* d_out, int out_size, void* d_ws,
                              size_t ws_size, hipStream_t stream) {
  const float* x  = (const float*)d_in[0];   // [8,2048,256] fp32
  const float* Wq = (const float*)d_in[1];   // [256,256] fp32
  const float* Wk = (const float*)d_in[2];   // [256,256] fp32
  float* out = (float*)d_out;

  const size_t n_x = (size_t)B_DIM * T_DIM * INNER;  // 4,194,304

  // Workspace layout (bf16): Q | K  (16.8 MB)
  bf16_t* Q = (bf16_t*)d_ws;
  bf16_t* K = Q + n_x;

  proj_kernel<<<512, 256, 0, stream>>>(x, Wq, Wk, Q, K);

  scores_kernel<<<2048, 256, 0, stream>>>(Q, K, out);
}